// Round 1
// baseline (838.628 us; speedup 1.0000x reference)
//
#include <hip/hip_runtime.h>
#include <hip/hip_bf16.h>
#include <stdint.h>
#include <math.h>

#define T_TOK 2048
#define DIM   2048
#define FDIM  2048
#define NE    8

#define BM 128
#define BN 128
#define BK 32
#define BROW 36   // padded B-tile row stride in u16 (72 B): keeps n4&3 in the bank fn
#define MATSZ 4194304ull  // 2048*2048

typedef unsigned short u16;
typedef unsigned int u32;
typedef short s16x8 __attribute__((ext_vector_type(8)));
typedef short s16x4 __attribute__((ext_vector_type(4)));
typedef float f32x4 __attribute__((ext_vector_type(4)));
typedef unsigned int u32x2 __attribute__((ext_vector_type(2)));

__device__ __forceinline__ u16 f2bf(float f) {
    union { float f; unsigned int u; } v; v.f = f;
    unsigned int r = v.u + 0x7FFFu + ((v.u >> 16) & 1u);  // RNE
    return (u16)(r >> 16);
}

// packed RNE f32x2 -> bf16x2 (v_cvt_pk_bf16_f32 on gfx950); low u16 = a
__device__ __forceinline__ u32 pkbf(float a, float b) {
    union { __hip_bfloat162 h; u32 u; } v;
    v.h = __float22bfloat162_rn(make_float2(a, b));
    return v.u;
}

// async 16B global -> LDS. lds ptr wave-uniform; HW deposits at base + lane*16.
__device__ __forceinline__ void gload_lds16(const void* g, void* l) {
    __builtin_amdgcn_global_load_lds((const __attribute__((address_space(1))) void*)g,
                                     (__attribute__((address_space(3))) void*)l, 16, 0, 0);
}

// ---------------- router ----------------
__global__ __launch_bounds__(256) void router_k(
    const float* __restrict__ x, const float* __restrict__ rw,
    float* __restrict__ score, int* __restrict__ eidx, int* __restrict__ counts)
{
    int t = blockIdx.x;
    int tid = threadIdx.x;
    float p[8] = {0.f,0.f,0.f,0.f,0.f,0.f,0.f,0.f};
    const float* xrow = x + (size_t)t * DIM;
    for (int d = tid; d < DIM; d += 256) {
        float xv = xrow[d];
        const float4* r = (const float4*)(rw + (size_t)d * 8);
        float4 r0 = r[0], r1 = r[1];
        p[0] += xv * r0.x; p[1] += xv * r0.y; p[2] += xv * r0.z; p[3] += xv * r0.w;
        p[4] += xv * r1.x; p[5] += xv * r1.y; p[6] += xv * r1.z; p[7] += xv * r1.w;
    }
    #pragma unroll
    for (int off = 32; off > 0; off >>= 1) {
        #pragma unroll
        for (int e = 0; e < 8; ++e) p[e] += __shfl_down(p[e], off);
    }
    __shared__ float red[4][8];
    int wave = tid >> 6, lane = tid & 63;
    if (lane == 0) {
        #pragma unroll
        for (int e = 0; e < 8; ++e) red[wave][e] = p[e];
    }
    __syncthreads();
    if (tid == 0) {
        float lg[8];
        #pragma unroll
        for (int e = 0; e < 8; ++e) lg[e] = red[0][e] + red[1][e] + red[2][e] + red[3][e];
        int best = 0; float bv = lg[0];
        #pragma unroll
        for (int e = 1; e < 8; ++e) { if (lg[e] > bv) { bv = lg[e]; best = e; } }
        score[t] = 1.f / (1.f + expf(-bv));
        eidx[t] = best;
        atomicAdd(&counts[best], 1);
    }
}

__global__ void scan_k(const int* __restrict__ counts, int* __restrict__ offs,
                       int* __restrict__ fill)
{
    if (threadIdx.x == 0 && blockIdx.x == 0) {
        int run = 0;
        for (int e = 0; e < NE; ++e) { offs[e] = run; fill[e] = run; run += counts[e]; }
    }
}

// ---------------- gather ----------------
__global__ __launch_bounds__(256) void gather_k(
    const float* __restrict__ x, const float* __restrict__ score,
    const int* __restrict__ eidx, int* __restrict__ fill,
    int* __restrict__ tokmap, u16* __restrict__ xsc, u16* __restrict__ xbf)
{
    int t = blockIdx.x, tid = threadIdx.x;
    __shared__ int sp;
    if (tid == 0) {
        int e = eidx[t];
        int p = atomicAdd(&fill[e], 1);
        tokmap[p] = t;
        sp = p;
    }
    __syncthreads();
    int pos = sp;
    float s = score[t];
    const float4* xr = (const float4*)(x + (size_t)t * DIM);
    float4 a = xr[tid * 2], b = xr[tid * 2 + 1];
    alignas(16) u16 raw[8] = { f2bf(a.x), f2bf(a.y), f2bf(a.z), f2bf(a.w),
                               f2bf(b.x), f2bf(b.y), f2bf(b.z), f2bf(b.w) };
    alignas(16) u16 scl[8] = { f2bf(a.x*s), f2bf(a.y*s), f2bf(a.z*s), f2bf(a.w*s),
                               f2bf(b.x*s), f2bf(b.y*s), f2bf(b.z*s), f2bf(b.w*s) };
    *(s16x8*)(xbf + (size_t)t * DIM + tid * 8)   = *(s16x8*)raw;
    *(s16x8*)(xsc + (size_t)pos * DIM + tid * 8) = *(s16x8*)scl;
}

// ============ fused gate/up GEMM: weights read as fp32 [K][N], converted +
// ============ transposed into LDS in-kernel (no wtrans pass). 128x128 tile,
// ============ 4 waves of 64x64 dual-acc (gate+up). A staged via global_load_lds.
// B LDS layout: row n (BROW=36 u16 stride), k-quad q (4 u16) stored at slot
// q ^ ((n>>4)&7)  -> write conflicts at the 4-way b64 floor, reads conflict-free.
__global__ __launch_bounds__(256) void gateup2_k(
    const u16* __restrict__ xsc, const u16* __restrict__ xbf,
    const float* __restrict__ gw, const float* __restrict__ uw,
    const float* __restrict__ sgw, const float* __restrict__ suw,
    const int* __restrict__ counts, const int* __restrict__ offs,
    u16* __restrict__ Hbf, u16* __restrict__ Hs)
{
    int bid = blockIdx.x;
    int g  = bid >> 8;          // 0..8 (8 = shared)
    int mt = (bid >> 4) & 15;
    int nt = bid & 15;

    int M; const u16* A; const float* Wg; const float* Wu; u16* Ho;
    if (g < NE) {
        M = counts[g];
        int ro = offs[g];
        A  = xsc + (size_t)ro * DIM;
        Wg = gw + (size_t)g * MATSZ;
        Wu = uw + (size_t)g * MATSZ;
        Ho = Hbf + (size_t)ro * FDIM;
    } else {
        M = T_TOK; A = xbf; Wg = sgw; Wu = suw; Ho = Hs;
    }
    int m0 = mt * BM;
    if (m0 >= M) return;
    int n0 = nt * BN;

    __shared__ __align__(128) u16 As[BM * BK];
    __shared__ __align__(128) u16 Bgs[BN * BROW];
    __shared__ __align__(128) u16 Bus[BN * BROW];

    int tid = threadIdx.x;
    int l = tid & 63;
    int w = tid >> 6;
    int wm = (w >> 1) * 64;
    int wn = (w & 1) * 64;

    f32x4 accg[4][4], accu[4][4];
    #pragma unroll
    for (int i = 0; i < 4; ++i)
        #pragma unroll
        for (int j = 0; j < 4; ++j) { accg[i][j] = (f32x4)0.f; accu[i][j] = (f32x4)0.f; }

    // A staging (bf16, async DMA): wave w covers rows [w*32, w*32+32)
    const u16* gA0 = A + (size_t)min(m0 + w*32 +      (l>>2), M-1)*DIM + (l&3)*8;
    const u16* gA1 = A + (size_t)min(m0 + w*32 + 16 + (l>>2), M-1)*DIM + (l&3)*8;
    u16* lA0 = As + (w*32)      * BK;
    u16* lA1 = As + (w*32 + 16) * BK;

    // B staging roles: thread owns 4x4 fp32 block (k-quad kq, n-quad n4)
    int n4 = tid & 31;
    int kq = tid >> 5;                              // 0..7
    int slot = (kq ^ ((n4 >> 2) & 7)) << 2;         // swizzled u16 offset in row
    const float* gBg = Wg + (size_t)(kq*4)*FDIM + n0 + n4*4;
    const float* gBu = Wu + (size_t)(kq*4)*FDIM + n0 + n4*4;
    u16* wBg = Bgs + (n4*4)*BROW + slot;
    u16* wBu = Bus + (n4*4)*BROW + slot;

    // fragment roles
    int am   = wm + (l & 15);
    int koff = (l >> 4) * 8;        // u16 offset in k
    int q0   = (l >> 4) * 2;        // base k-quad of the fragment
    int wnq  = wn >> 4;

    for (int k0 = 0; k0 < DIM; k0 += BK) {
        __syncthreads();            // prev iteration's fragment reads complete
        gload_lds16(gA0, lA0);
        gload_lds16(gA1, lA1);
        gA0 += BK; gA1 += BK;
        f32x4 b0 = *(const f32x4*)(gBg);
        f32x4 b1 = *(const f32x4*)(gBg + FDIM);
        f32x4 b2 = *(const f32x4*)(gBg + 2*FDIM);
        f32x4 b3 = *(const f32x4*)(gBg + 3*FDIM);
        f32x4 c0 = *(const f32x4*)(gBu);
        f32x4 c1 = *(const f32x4*)(gBu + FDIM);
        f32x4 c2 = *(const f32x4*)(gBu + 2*FDIM);
        f32x4 c3 = *(const f32x4*)(gBu + 3*FDIM);
        gBg += (size_t)BK * FDIM; gBu += (size_t)BK * FDIM;
        #pragma unroll
        for (int j = 0; j < 4; ++j) {
            u32x2 vg = { pkbf(b0[j], b1[j]), pkbf(b2[j], b3[j]) };
            u32x2 vu = { pkbf(c0[j], c1[j]), pkbf(c2[j], c3[j]) };
            *(u32x2*)(wBg + j*BROW) = vg;
            *(u32x2*)(wBu + j*BROW) = vu;
        }
        __syncthreads();            // drains gload + B loads + ds_writes

        s16x8 af0 = *(const s16x8*)&As[(am     ) * BK + koff];
        s16x8 af1 = *(const s16x8*)&As[(am + 16) * BK + koff];
        s16x8 af2 = *(const s16x8*)&As[(am + 32) * BK + koff];
        s16x8 af3 = *(const s16x8*)&As[(am + 48) * BK + koff];
        #pragma unroll
        for (int j = 0; j < 4; ++j) {
            int bc = wn + j*16 + (l & 15);
            int sj = (wnq + j) & 7;                 // == (bc>>4)&7, wave-uniform
            const u16* rg = &Bgs[bc * BROW];
            const u16* ru = &Bus[bc * BROW];
            s16x4 glo = *(const s16x4*)(rg + (((q0    ) ^ sj) << 2));
            s16x4 ghi = *(const s16x4*)(rg + (((q0 + 1) ^ sj) << 2));
            s16x4 ulo = *(const s16x4*)(ru + (((q0    ) ^ sj) << 2));
            s16x4 uhi = *(const s16x4*)(ru + (((q0 + 1) ^ sj) << 2));
            s16x8 bgf = __builtin_shufflevector(glo, ghi, 0,1,2,3,4,5,6,7);
            s16x8 buf_ = __builtin_shufflevector(ulo, uhi, 0,1,2,3,4,5,6,7);
            accg[0][j] = __builtin_amdgcn_mfma_f32_16x16x32_bf16(af0, bgf, accg[0][j], 0, 0, 0);
            accg[1][j] = __builtin_amdgcn_mfma_f32_16x16x32_bf16(af1, bgf, accg[1][j], 0, 0, 0);
            accg[2][j] = __builtin_amdgcn_mfma_f32_16x16x32_bf16(af2, bgf, accg[2][j], 0, 0, 0);
            accg[3][j] = __builtin_amdgcn_mfma_f32_16x16x32_bf16(af3, bgf, accg[3][j], 0, 0, 0);
            accu[0][j] = __builtin_amdgcn_mfma_f32_16x16x32_bf16(af0, buf_, accu[0][j], 0, 0, 0);
            accu[1][j] = __builtin_amdgcn_mfma_f32_16x16x32_bf16(af1, buf_, accu[1][j], 0, 0, 0);
            accu[2][j] = __builtin_amdgcn_mfma_f32_16x16x32_bf16(af2, buf_, accu[2][j], 0, 0, 0);
            accu[3][j] = __builtin_amdgcn_mfma_f32_16x16x32_bf16(af3, buf_, accu[3][j], 0, 0, 0);
        }
    }

    int rbase = m0 + wm + ((l >> 4) << 2);
    int cbase = n0 + wn + (l & 15);
    #pragma unroll
    for (int i = 0; i < 4; ++i) {
        #pragma unroll
        for (int j = 0; j < 4; ++j) {
            #pragma unroll
            for (int r = 0; r < 4; ++r) {
                int row = rbase + i*16 + r;
                if (row < M) {
                    float gv = accg[i][j][r];
                    float uv = accu[i][j][r];
                    float h = gv / (1.f + expf(-gv)) * uv;
                    Ho[(size_t)row * FDIM + cbase + j*16] = f2bf(h);
                }
            }
        }
    }
}

// ============ fused down GEMM: same structure, single accumulator.
// shared pass stores out f32; expert pass RMWs (token,col owned by one expert;
// shared pass completed earlier on the same stream).
__global__ __launch_bounds__(256) void down2_k(
    const u16* __restrict__ Hbf, const u16* __restrict__ Hs,
    const float* __restrict__ dwn, const float* __restrict__ sdw,
    const int* __restrict__ counts, const int* __restrict__ offs,
    const int* __restrict__ tokmap, float* __restrict__ out, int shared_pass)
{
    int bid = blockIdx.x;
    int mt, nt, M, ro; const u16* A; const float* W;
    if (shared_pass) {
        mt = bid >> 4; nt = bid & 15;
        M = T_TOK; ro = 0; A = Hs; W = sdw;
    } else {
        int g = bid >> 8; mt = (bid >> 4) & 15; nt = bid & 15;
        M = counts[g]; ro = offs[g];
        A = Hbf + (size_t)ro * FDIM;
        W = dwn + (size_t)g * MATSZ;
    }
    int m0 = mt * BM;
    if (m0 >= M) return;
    int n0 = nt * BN;

    __shared__ __align__(128) u16 As[BM * BK];
    __shared__ __align__(128) u16 Bds[BN * BROW];

    int tid = threadIdx.x;
    int l = tid & 63;
    int w = tid >> 6;
    int wm = (w >> 1) * 64;
    int wn = (w & 1) * 64;

    f32x4 acc[4][4];
    #pragma unroll
    for (int i = 0; i < 4; ++i)
        #pragma unroll
        for (int j = 0; j < 4; ++j) acc[i][j] = (f32x4)0.f;

    const u16* gA0 = A + (size_t)min(m0 + w*32 +      (l>>2), M-1)*FDIM + (l&3)*8;
    const u16* gA1 = A + (size_t)min(m0 + w*32 + 16 + (l>>2), M-1)*FDIM + (l&3)*8;
    u16* lA0 = As + (w*32)      * BK;
    u16* lA1 = As + (w*32 + 16) * BK;

    int n4 = tid & 31;
    int kq = tid >> 5;
    int slot = (kq ^ ((n4 >> 2) & 7)) << 2;
    const float* gB = W + (size_t)(kq*4)*DIM + n0 + n4*4;
    u16* wB = Bds + (n4*4)*BROW + slot;

    int am   = wm + (l & 15);
    int koff = (l >> 4) * 8;
    int q0   = (l >> 4) * 2;
    int wnq  = wn >> 4;

    for (int k0 = 0; k0 < FDIM; k0 += BK) {
        __syncthreads();
        gload_lds16(gA0, lA0);
        gload_lds16(gA1, lA1);
        gA0 += BK; gA1 += BK;
        f32x4 b0 = *(const f32x4*)(gB);
        f32x4 b1 = *(const f32x4*)(gB + DIM);
        f32x4 b2 = *(const f32x4*)(gB + 2*DIM);
        f32x4 b3 = *(const f32x4*)(gB + 3*DIM);
        gB += (size_t)BK * DIM;
        #pragma unroll
        for (int j = 0; j < 4; ++j) {
            u32x2 vb = { pkbf(b0[j], b1[j]), pkbf(b2[j], b3[j]) };
            *(u32x2*)(wB + j*BROW) = vb;
        }
        __syncthreads();

        s16x8 af0 = *(const s16x8*)&As[(am     ) * BK + koff];
        s16x8 af1 = *(const s16x8*)&As[(am + 16) * BK + koff];
        s16x8 af2 = *(const s16x8*)&As[(am + 32) * BK + koff];
        s16x8 af3 = *(const s16x8*)&As[(am + 48) * BK + koff];
        #pragma unroll
        for (int j = 0; j < 4; ++j) {
            int bc = wn + j*16 + (l & 15);
            int sj = (wnq + j) & 7;
            const u16* rb = &Bds[bc * BROW];
            s16x4 blo = *(const s16x4*)(rb + (((q0    ) ^ sj) << 2));
            s16x4 bhi = *(const s16x4*)(rb + (((q0 + 1) ^ sj) << 2));
            s16x8 bdf = __builtin_shufflevector(blo, bhi, 0,1,2,3,4,5,6,7);
            acc[0][j] = __builtin_amdgcn_mfma_f32_16x16x32_bf16(af0, bdf, acc[0][j], 0, 0, 0);
            acc[1][j] = __builtin_amdgcn_mfma_f32_16x16x32_bf16(af1, bdf, acc[1][j], 0, 0, 0);
            acc[2][j] = __builtin_amdgcn_mfma_f32_16x16x32_bf16(af2, bdf, acc[2][j], 0, 0, 0);
            acc[3][j] = __builtin_amdgcn_mfma_f32_16x16x32_bf16(af3, bdf, acc[3][j], 0, 0, 0);
        }
    }

    int rbase = m0 + wm + ((l >> 4) << 2);
    int cbase = n0 + wn + (l & 15);
    #pragma unroll
    for (int i = 0; i < 4; ++i) {
        #pragma unroll
        for (int r = 0; r < 4; ++r) {
            int row = rbase + i*16 + r;
            if (row < M) {
                if (shared_pass) {
                    float* dst = out + (size_t)row * DIM;
                    #pragma unroll
                    for (int j = 0; j < 4; ++j) dst[cbase + j*16] = acc[i][j][r];
                } else {
                    float* dst = out + (size_t)tokmap[ro + row] * DIM;
                    #pragma unroll
                    for (int j = 0; j < 4; ++j)
                        dst[cbase + j*16] = dst[cbase + j*16] + acc[i][j][r];
                }
            }
        }
    }
}

// ======================= host =======================
extern "C" void kernel_launch(void* const* d_in, const int* in_sizes, int n_in,
                              void* d_out, int out_size, void* d_ws, size_t ws_size,
                              hipStream_t stream) {
    const float* x   = (const float*)d_in[0];
    const float* rw  = (const float*)d_in[1];
    const float* gw  = (const float*)d_in[2];
    const float* uw  = (const float*)d_in[3];
    const float* dwn = (const float*)d_in[4];
    const float* sgw = (const float*)d_in[5];
    const float* suw = (const float*)d_in[6];
    const float* sdw = (const float*)d_in[7];
    float* out = (float*)d_out;

    char* ws = (char*)d_ws;
    float* score = (float*)(ws);
    int* eidx    = (int*)(ws + 8192);
    int* counts  = (int*)(ws + 16384);
    int* fill    = (int*)(ws + 16448);
    int* offs    = (int*)(ws + 16512);
    int* tokmap  = (int*)(ws + 16576);
    u16* xsc = (u16*)(ws + 32768);
    u16* xbf = xsc + MATSZ;
    u16* Hbf = xbf + MATSZ;
    u16* Hs  = Hbf + MATSZ;

    hipMemsetAsync(counts, 0, 128, stream);   // counts + fill

    router_k<<<T_TOK, 256, 0, stream>>>(x, rw, score, eidx, counts);
    scan_k<<<1, 64, 0, stream>>>(counts, offs, fill);
    gather_k<<<T_TOK, 256, 0, stream>>>(x, score, eidx, fill, tokmap, xsc, xbf);

    // fused GEMMs: fp32 weights converted+transposed in-kernel (no wtrans pass)
    gateup2_k<<<9 * 256, 256, 0, stream>>>(xsc, xbf, gw, uw, sgw, suw, counts, offs, Hbf, Hs);
    down2_k<<<256, 256, 0, stream>>>(Hbf, Hs, dwn, sdw, counts, offs, tokmap, out, 1);
    down2_k<<<8 * 256, 256, 0, stream>>>(Hbf, Hs, dwn, sdw, counts, offs, tokmap, out, 0);
}

// Round 2
// 663.559 us; speedup vs baseline: 1.2638x; 1.2638x over previous
//
#include <hip/hip_runtime.h>
#include <hip/hip_bf16.h>
#include <stdint.h>
#include <math.h>

#define T_TOK 2048
#define DIM   2048
#define FDIM  2048
#define NE    8

#define BM 128
#define BN 128
#define BK 32
#define BROW 36            // padded B-tile row stride in u16 (72 B)
#define ASZ (BM * BK)      // 4096 u16 per LDS half (A)
#define BSZ (BN * BROW)    // 4608 u16 per LDS half (B)
#define MATSZ 4194304ull   // 2048*2048

typedef unsigned short u16;
typedef unsigned int u32;
typedef short s16x8 __attribute__((ext_vector_type(8)));
typedef short s16x4 __attribute__((ext_vector_type(4)));
typedef float f32x4 __attribute__((ext_vector_type(4)));
typedef unsigned int u32x2 __attribute__((ext_vector_type(2)));

__device__ __forceinline__ u16 f2bf(float f) {
    union { float f; unsigned int u; } v; v.f = f;
    unsigned int r = v.u + 0x7FFFu + ((v.u >> 16) & 1u);  // RNE
    return (u16)(r >> 16);
}

// packed RNE f32x2 -> bf16x2 (v_cvt_pk_bf16_f32 on gfx950); low u16 = a
__device__ __forceinline__ u32 pkbf(float a, float b) {
    union { __hip_bfloat162 h; u32 u; } v;
    v.h = __float22bfloat162_rn(make_float2(a, b));
    return v.u;
}

// one barrier per K-step: lgkmcnt(0) (my ds ops done, incl. prev-iter frag reads)
// then s_barrier. NO vmcnt drain -> prefetch global loads stay in flight.
// "memory" clobber pins compiler ds_read/ds_write ordering across it.
__device__ __forceinline__ void tile_barrier() {
    asm volatile("s_waitcnt lgkmcnt(0)\n\ts_barrier" ::: "memory");
}

// ---------------- router ----------------
__global__ __launch_bounds__(256) void router_k(
    const float* __restrict__ x, const float* __restrict__ rw,
    float* __restrict__ score, int* __restrict__ eidx, int* __restrict__ counts)
{
    int t = blockIdx.x;
    int tid = threadIdx.x;
    float p[8] = {0.f,0.f,0.f,0.f,0.f,0.f,0.f,0.f};
    const float* xrow = x + (size_t)t * DIM;
    for (int d = tid; d < DIM; d += 256) {
        float xv = xrow[d];
        const float4* r = (const float4*)(rw + (size_t)d * 8);
        float4 r0 = r[0], r1 = r[1];
        p[0] += xv * r0.x; p[1] += xv * r0.y; p[2] += xv * r0.z; p[3] += xv * r0.w;
        p[4] += xv * r1.x; p[5] += xv * r1.y; p[6] += xv * r1.z; p[7] += xv * r1.w;
    }
    #pragma unroll
    for (int off = 32; off > 0; off >>= 1) {
        #pragma unroll
        for (int e = 0; e < 8; ++e) p[e] += __shfl_down(p[e], off);
    }
    __shared__ float red[4][8];
    int wave = tid >> 6, lane = tid & 63;
    if (lane == 0) {
        #pragma unroll
        for (int e = 0; e < 8; ++e) red[wave][e] = p[e];
    }
    __syncthreads();
    if (tid == 0) {
        float lg[8];
        #pragma unroll
        for (int e = 0; e < 8; ++e) lg[e] = red[0][e] + red[1][e] + red[2][e] + red[3][e];
        int best = 0; float bv = lg[0];
        #pragma unroll
        for (int e = 1; e < 8; ++e) { if (lg[e] > bv) { bv = lg[e]; best = e; } }
        score[t] = 1.f / (1.f + expf(-bv));
        eidx[t] = best;
        atomicAdd(&counts[best], 1);
    }
}

__global__ void scan_k(const int* __restrict__ counts, int* __restrict__ offs,
                       int* __restrict__ fill)
{
    if (threadIdx.x == 0 && blockIdx.x == 0) {
        int run = 0;
        for (int e = 0; e < NE; ++e) { offs[e] = run; fill[e] = run; run += counts[e]; }
    }
}

// ---------------- gather ----------------
__global__ __launch_bounds__(256) void gather_k(
    const float* __restrict__ x, const float* __restrict__ score,
    const int* __restrict__ eidx, int* __restrict__ fill,
    int* __restrict__ tokmap, u16* __restrict__ xsc, u16* __restrict__ xbf)
{
    int t = blockIdx.x, tid = threadIdx.x;
    __shared__ int sp;
    if (tid == 0) {
        int e = eidx[t];
        int p = atomicAdd(&fill[e], 1);
        tokmap[p] = t;
        sp = p;
    }
    __syncthreads();
    int pos = sp;
    float s = score[t];
    const float4* xr = (const float4*)(x + (size_t)t * DIM);
    float4 a = xr[tid * 2], b = xr[tid * 2 + 1];
    alignas(16) u16 raw[8] = { f2bf(a.x), f2bf(a.y), f2bf(a.z), f2bf(a.w),
                               f2bf(b.x), f2bf(b.y), f2bf(b.z), f2bf(b.w) };
    alignas(16) u16 scl[8] = { f2bf(a.x*s), f2bf(a.y*s), f2bf(a.z*s), f2bf(a.w*s),
                               f2bf(b.x*s), f2bf(b.y*s), f2bf(b.z*s), f2bf(b.w*s) };
    *(s16x8*)(xbf + (size_t)t * DIM + tid * 8)   = *(s16x8*)raw;
    *(s16x8*)(xsc + (size_t)pos * DIM + tid * 8) = *(s16x8*)scl;
}

// ============ fused gate/up GEMM, software-pipelined ============
// fp32 weights converted+transposed into LDS in-kernel (no wtrans pass).
// Pipeline: prefetch tile t+1 (global->regs) issued BEFORE tile t's MFMA phase;
// double-buffered LDS; one raw barrier per K-step (no vmcnt drain).
// B LDS layout: row n (BROW stride), k-quad q stored at slot q ^ ((n>>4... )&7).
__global__ __launch_bounds__(256) void gateup3_k(
    const u16* __restrict__ xsc, const u16* __restrict__ xbf,
    const float* __restrict__ gw, const float* __restrict__ uw,
    const float* __restrict__ sgw, const float* __restrict__ suw,
    const int* __restrict__ counts, const int* __restrict__ offs,
    u16* __restrict__ Hbf, u16* __restrict__ Hs)
{
    int bid = blockIdx.x;
    int g  = bid >> 8;          // 0..8 (8 = shared)
    int mt = (bid >> 4) & 15;
    int nt = bid & 15;

    int M; const u16* A; const float* Wg; const float* Wu; u16* Ho;
    if (g < NE) {
        M = counts[g];
        int ro = offs[g];
        A  = xsc + (size_t)ro * DIM;
        Wg = gw + (size_t)g * MATSZ;
        Wu = uw + (size_t)g * MATSZ;
        Ho = Hbf + (size_t)ro * FDIM;
    } else {
        M = T_TOK; A = xbf; Wg = sgw; Wu = suw; Ho = Hs;
    }
    int m0 = mt * BM;
    if (m0 >= M) return;
    int n0 = nt * BN;

    __shared__ __align__(128) u16 As[2 * ASZ];
    __shared__ __align__(128) u16 Bgs[2 * BSZ];
    __shared__ __align__(128) u16 Bus[2 * BSZ];

    int tid = threadIdx.x;
    int l = tid & 63;
    int w = tid >> 6;
    int wm = (w >> 1) * 64;
    int wn = (w & 1) * 64;

    f32x4 accg[4][4], accu[4][4];
    #pragma unroll
    for (int i = 0; i < 4; ++i)
        #pragma unroll
        for (int j = 0; j < 4; ++j) { accg[i][j] = (f32x4)0.f; accu[i][j] = (f32x4)0.f; }

    // --- A staging (bf16, reg-staged): wave w covers rows [w*32, w*32+32) ---
    int ar0 = w*32 + (l >> 2);
    const u16* gA0 = A + (size_t)min(m0 + ar0,      M-1)*DIM + (l&3)*8;
    const u16* gA1 = A + (size_t)min(m0 + ar0 + 16, M-1)*DIM + (l&3)*8;
    int aoff0 = ar0 * BK + (l&3)*8;
    int aoff1 = aoff0 + 16 * BK;

    // --- B staging roles: thread owns 4x4 fp32 block (k-quad kq, n-quad n4) ---
    int n4 = tid & 31;
    int kq = tid >> 5;                              // 0..7
    int slot = (kq ^ ((n4 >> 2) & 7)) << 2;         // swizzled u16 offset in row
    const float* gBg = Wg + (size_t)(kq*4)*FDIM + n0 + n4*4;
    const float* gBu = Wu + (size_t)(kq*4)*FDIM + n0 + n4*4;
    int bwoff = (n4*4)*BROW + slot;

    // --- fragment roles ---
    int am   = wm + (l & 15);
    int koff = (l >> 4) * 8;        // u16 offset in k
    int q0   = (l >> 4) * 2;        // base k-quad of the fragment
    int wnq  = wn >> 4;

    // --- prologue: load tile 0 into regs ---
    s16x8 ra0 = *(const s16x8*)gA0;  gA0 += BK;
    s16x8 ra1 = *(const s16x8*)gA1;  gA1 += BK;
    f32x4 b0 = *(const f32x4*)(gBg);
    f32x4 b1 = *(const f32x4*)(gBg + FDIM);
    f32x4 b2 = *(const f32x4*)(gBg + 2*FDIM);
    f32x4 b3 = *(const f32x4*)(gBg + 3*FDIM);
    gBg += (size_t)BK * FDIM;
    f32x4 c0 = *(const f32x4*)(gBu);
    f32x4 c1 = *(const f32x4*)(gBu + FDIM);
    f32x4 c2 = *(const f32x4*)(gBu + 2*FDIM);
    f32x4 c3 = *(const f32x4*)(gBu + 3*FDIM);
    gBu += (size_t)BK * FDIM;

    int cur = 0;
    for (int k0 = 0; k0 < DIM; k0 += BK) {
        // ---- write staged tile t into LDS buf[cur] (vmcnt waits auto-inserted) ----
        u16* As_c = As + cur * ASZ;
        *(s16x8*)&As_c[aoff0] = ra0;
        *(s16x8*)&As_c[aoff1] = ra1;
        u16* wBg = Bgs + cur * BSZ + bwoff;
        u16* wBu = Bus + cur * BSZ + bwoff;
        #pragma unroll
        for (int j = 0; j < 4; ++j) {
            u32x2 vg = { pkbf(b0[j], b1[j]), pkbf(b2[j], b3[j]) };
            u32x2 vu = { pkbf(c0[j], c1[j]), pkbf(c2[j], c3[j]) };
            *(u32x2*)(wBg + j*BROW) = vg;
            *(u32x2*)(wBu + j*BROW) = vu;
        }
        // ---- issue tile t+1 loads; they fly across the barrier + MFMA phase ----
        if (k0 + BK < DIM) {
            ra0 = *(const s16x8*)gA0;  gA0 += BK;
            ra1 = *(const s16x8*)gA1;  gA1 += BK;
            b0 = *(const f32x4*)(gBg);
            b1 = *(const f32x4*)(gBg + FDIM);
            b2 = *(const f32x4*)(gBg + 2*FDIM);
            b3 = *(const f32x4*)(gBg + 3*FDIM);
            gBg += (size_t)BK * FDIM;
            c0 = *(const f32x4*)(gBu);
            c1 = *(const f32x4*)(gBu + FDIM);
            c2 = *(const f32x4*)(gBu + 2*FDIM);
            c3 = *(const f32x4*)(gBu + 3*FDIM);
            gBu += (size_t)BK * FDIM;
        }
        tile_barrier();

        // ---- MFMA phase on buf[cur] ----
        __builtin_amdgcn_s_setprio(1);
        const u16* As_r = As + cur * ASZ;
        s16x8 af0 = *(const s16x8*)&As_r[(am     ) * BK + koff];
        s16x8 af1 = *(const s16x8*)&As_r[(am + 16) * BK + koff];
        s16x8 af2 = *(const s16x8*)&As_r[(am + 32) * BK + koff];
        s16x8 af3 = *(const s16x8*)&As_r[(am + 48) * BK + koff];
        const u16* Bg_r = Bgs + cur * BSZ;
        const u16* Bu_r = Bus + cur * BSZ;
        #pragma unroll
        for (int j = 0; j < 4; ++j) {
            int bc = wn + j*16 + (l & 15);
            int sj = (wnq + j) & 7;                 // == (bc>>4)&7, wave-uniform
            const u16* rg = &Bg_r[bc * BROW];
            const u16* ru = &Bu_r[bc * BROW];
            s16x4 glo = *(const s16x4*)(rg + (((q0    ) ^ sj) << 2));
            s16x4 ghi = *(const s16x4*)(rg + (((q0 + 1) ^ sj) << 2));
            s16x4 ulo = *(const s16x4*)(ru + (((q0    ) ^ sj) << 2));
            s16x4 uhi = *(const s16x4*)(ru + (((q0 + 1) ^ sj) << 2));
            s16x8 bgf = __builtin_shufflevector(glo, ghi, 0,1,2,3,4,5,6,7);
            s16x8 buf_ = __builtin_shufflevector(ulo, uhi, 0,1,2,3,4,5,6,7);
            accg[0][j] = __builtin_amdgcn_mfma_f32_16x16x32_bf16(af0, bgf, accg[0][j], 0, 0, 0);
            accg[1][j] = __builtin_amdgcn_mfma_f32_16x16x32_bf16(af1, bgf, accg[1][j], 0, 0, 0);
            accg[2][j] = __builtin_amdgcn_mfma_f32_16x16x32_bf16(af2, bgf, accg[2][j], 0, 0, 0);
            accg[3][j] = __builtin_amdgcn_mfma_f32_16x16x32_bf16(af3, bgf, accg[3][j], 0, 0, 0);
            accu[0][j] = __builtin_amdgcn_mfma_f32_16x16x32_bf16(af0, buf_, accu[0][j], 0, 0, 0);
            accu[1][j] = __builtin_amdgcn_mfma_f32_16x16x32_bf16(af1, buf_, accu[1][j], 0, 0, 0);
            accu[2][j] = __builtin_amdgcn_mfma_f32_16x16x32_bf16(af2, buf_, accu[2][j], 0, 0, 0);
            accu[3][j] = __builtin_amdgcn_mfma_f32_16x16x32_bf16(af3, buf_, accu[3][j], 0, 0, 0);
        }
        __builtin_amdgcn_s_setprio(0);
        cur ^= 1;
    }

    int rbase = m0 + wm + ((l >> 4) << 2);
    int cbase = n0 + wn + (l & 15);
    #pragma unroll
    for (int i = 0; i < 4; ++i) {
        #pragma unroll
        for (int j = 0; j < 4; ++j) {
            #pragma unroll
            for (int r = 0; r < 4; ++r) {
                int row = rbase + i*16 + r;
                if (row < M) {
                    float gv = accg[i][j][r];
                    float uv = accu[i][j][r];
                    float h = gv / (1.f + expf(-gv)) * uv;
                    Ho[(size_t)row * FDIM + cbase + j*16] = f2bf(h);
                }
            }
        }
    }
}

// ============ fused down GEMM, software-pipelined (same schedule) ============
__global__ __launch_bounds__(256) void down3_k(
    const u16* __restrict__ Hbf, const u16* __restrict__ Hs,
    const float* __restrict__ dwn, const float* __restrict__ sdw,
    const int* __restrict__ counts, const int* __restrict__ offs,
    const int* __restrict__ tokmap, float* __restrict__ out, int shared_pass)
{
    int bid = blockIdx.x;
    int mt, nt, M, ro; const u16* A; const float* W;
    if (shared_pass) {
        mt = bid >> 4; nt = bid & 15;
        M = T_TOK; ro = 0; A = Hs; W = sdw;
    } else {
        int g = bid >> 8; mt = (bid >> 4) & 15; nt = bid & 15;
        M = counts[g]; ro = offs[g];
        A = Hbf + (size_t)ro * FDIM;
        W = dwn + (size_t)g * MATSZ;
    }
    int m0 = mt * BM;
    if (m0 >= M) return;
    int n0 = nt * BN;

    __shared__ __align__(128) u16 As[2 * ASZ];
    __shared__ __align__(128) u16 Bds[2 * BSZ];

    int tid = threadIdx.x;
    int l = tid & 63;
    int w = tid >> 6;
    int wm = (w >> 1) * 64;
    int wn = (w & 1) * 64;

    f32x4 acc[4][4];
    #pragma unroll
    for (int i = 0; i < 4; ++i)
        #pragma unroll
        for (int j = 0; j < 4; ++j) acc[i][j] = (f32x4)0.f;

    int ar0 = w*32 + (l >> 2);
    const u16* gA0 = A + (size_t)min(m0 + ar0,      M-1)*FDIM + (l&3)*8;
    const u16* gA1 = A + (size_t)min(m0 + ar0 + 16, M-1)*FDIM + (l&3)*8;
    int aoff0 = ar0 * BK + (l&3)*8;
    int aoff1 = aoff0 + 16 * BK;

    int n4 = tid & 31;
    int kq = tid >> 5;
    int slot = (kq ^ ((n4 >> 2) & 7)) << 2;
    const float* gB = W + (size_t)(kq*4)*DIM + n0 + n4*4;
    int bwoff = (n4*4)*BROW + slot;

    int am   = wm + (l & 15);
    int koff = (l >> 4) * 8;
    int q0   = (l >> 4) * 2;
    int wnq  = wn >> 4;

    // prologue
    s16x8 ra0 = *(const s16x8*)gA0;  gA0 += BK;
    s16x8 ra1 = *(const s16x8*)gA1;  gA1 += BK;
    f32x4 b0 = *(const f32x4*)(gB);
    f32x4 b1 = *(const f32x4*)(gB + DIM);
    f32x4 b2 = *(const f32x4*)(gB + 2*DIM);
    f32x4 b3 = *(const f32x4*)(gB + 3*DIM);
    gB += (size_t)BK * DIM;

    int cur = 0;
    for (int k0 = 0; k0 < FDIM; k0 += BK) {
        u16* As_c = As + cur * ASZ;
        *(s16x8*)&As_c[aoff0] = ra0;
        *(s16x8*)&As_c[aoff1] = ra1;
        u16* wB = Bds + cur * BSZ + bwoff;
        #pragma unroll
        for (int j = 0; j < 4; ++j) {
            u32x2 vb = { pkbf(b0[j], b1[j]), pkbf(b2[j], b3[j]) };
            *(u32x2*)(wB + j*BROW) = vb;
        }
        if (k0 + BK < FDIM) {
            ra0 = *(const s16x8*)gA0;  gA0 += BK;
            ra1 = *(const s16x8*)gA1;  gA1 += BK;
            b0 = *(const f32x4*)(gB);
            b1 = *(const f32x4*)(gB + DIM);
            b2 = *(const f32x4*)(gB + 2*DIM);
            b3 = *(const f32x4*)(gB + 3*DIM);
            gB += (size_t)BK * DIM;
        }
        tile_barrier();

        __builtin_amdgcn_s_setprio(1);
        const u16* As_r = As + cur * ASZ;
        s16x8 af0 = *(const s16x8*)&As_r[(am     ) * BK + koff];
        s16x8 af1 = *(const s16x8*)&As_r[(am + 16) * BK + koff];
        s16x8 af2 = *(const s16x8*)&As_r[(am + 32) * BK + koff];
        s16x8 af3 = *(const s16x8*)&As_r[(am + 48) * BK + koff];
        const u16* Bd_r = Bds + cur * BSZ;
        #pragma unroll
        for (int j = 0; j < 4; ++j) {
            int bc = wn + j*16 + (l & 15);
            int sj = (wnq + j) & 7;
            const u16* rb = &Bd_r[bc * BROW];
            s16x4 blo = *(const s16x4*)(rb + (((q0    ) ^ sj) << 2));
            s16x4 bhi = *(const s16x4*)(rb + (((q0 + 1) ^ sj) << 2));
            s16x8 bdf = __builtin_shufflevector(blo, bhi, 0,1,2,3,4,5,6,7);
            acc[0][j] = __builtin_amdgcn_mfma_f32_16x16x32_bf16(af0, bdf, acc[0][j], 0, 0, 0);
            acc[1][j] = __builtin_amdgcn_mfma_f32_16x16x32_bf16(af1, bdf, acc[1][j], 0, 0, 0);
            acc[2][j] = __builtin_amdgcn_mfma_f32_16x16x32_bf16(af2, bdf, acc[2][j], 0, 0, 0);
            acc[3][j] = __builtin_amdgcn_mfma_f32_16x16x32_bf16(af3, bdf, acc[3][j], 0, 0, 0);
        }
        __builtin_amdgcn_s_setprio(0);
        cur ^= 1;
    }

    int rbase = m0 + wm + ((l >> 4) << 2);
    int cbase = n0 + wn + (l & 15);
    #pragma unroll
    for (int i = 0; i < 4; ++i) {
        #pragma unroll
        for (int r = 0; r < 4; ++r) {
            int row = rbase + i*16 + r;
            if (row < M) {
                if (shared_pass) {
                    float* dst = out + (size_t)row * DIM;
                    #pragma unroll
                    for (int j = 0; j < 4; ++j) dst[cbase + j*16] = acc[i][j][r];
                } else {
                    // (token,col) owned by exactly one expert block; shared pass
                    // completed earlier on the same stream -> safe non-atomic RMW.
                    float* dst = out + (size_t)tokmap[ro + row] * DIM;
                    #pragma unroll
                    for (int j = 0; j < 4; ++j)
                        dst[cbase + j*16] = dst[cbase + j*16] + acc[i][j][r];
                }
            }
        }
    }
}

// ======================= host =======================
extern "C" void kernel_launch(void* const* d_in, const int* in_sizes, int n_in,
                              void* d_out, int out_size, void* d_ws, size_t ws_size,
                              hipStream_t stream) {
    const float* x   = (const float*)d_in[0];
    const float* rw  = (const float*)d_in[1];
    const float* gw  = (const float*)d_in[2];
    const float* uw  = (const float*)d_in[3];
    const float* dwn = (const float*)d_in[4];
    const float* sgw = (const float*)d_in[5];
    const float* suw = (const float*)d_in[6];
    const float* sdw = (const float*)d_in[7];
    float* out = (float*)d_out;

    char* ws = (char*)d_ws;
    float* score = (float*)(ws);
    int* eidx    = (int*)(ws + 8192);
    int* counts  = (int*)(ws + 16384);
    int* fill    = (int*)(ws + 16448);
    int* offs    = (int*)(ws + 16512);
    int* tokmap  = (int*)(ws + 16576);
    u16* xsc = (u16*)(ws + 32768);
    u16* xbf = xsc + MATSZ;
    u16* Hbf = xbf + MATSZ;
    u16* Hs  = Hbf + MATSZ;

    hipMemsetAsync(counts, 0, 128, stream);   // counts + fill

    router_k<<<T_TOK, 256, 0, stream>>>(x, rw, score, eidx, counts);
    scan_k<<<1, 64, 0, stream>>>(counts, offs, fill);
    gather_k<<<T_TOK, 256, 0, stream>>>(x, score, eidx, fill, tokmap, xsc, xbf);

    // fused GEMMs: fp32 weights converted+transposed in-kernel, pipelined staging
    gateup3_k<<<9 * 256, 256, 0, stream>>>(xsc, xbf, gw, uw, sgw, suw, counts, offs, Hbf, Hs);
    down3_k<<<256, 256, 0, stream>>>(Hbf, Hs, dwn, sdw, counts, offs, tokmap, out, 1);
    down3_k<<<8 * 256, 256, 0, stream>>>(Hbf, Hs, dwn, sdw, counts, offs, tokmap, out, 0);
}